// Round 2
// baseline (82.709 us; speedup 1.0000x reference)
//
#include <hip/hip_runtime.h>

// PartialMatchingLoss: mean over (b,m) of min_n ||partial[b,m] - completed[b,n]||
// B=8, M=4096 (partial), N=8192 (completed), D=3, fp32.
//
// f(n) = 0.5*||c||^2 - p.c  (3 FMA per pair); n's processed in pairs,
// fminf(fm, fminf(f0,f1)) -> v_min3_f32: 3.5 VALU ops/pair.
// VALU-issue floor: 268.4M pairs * 3.5 / 78.6e12 ~= 12 us.
//
// R7 (re-run; R7 bench was an infra failure, container died twice):
//  (a) main occupancy 2->4 blocks/CU (NBLK 256->128, NC 32->64, 1024 blocks,
//      4 waves/SIMD) to cover ds_read/lgkmcnt stalls that capped issue at ~30%;
//  (b) reduce rewritten as float4-across-4-rows: 64 coalesced float4 loads
//      per thread (was 32 scalar strided), 128 single-wave blocks across 128 CUs.

constexpr int B  = 8;
constexpr int N  = 8192;           // completed points per batch
constexpr int M  = 4096;           // partial points per batch
constexpr int NT = 256;            // threads per block (main)
constexpr int TP = 8;              // partial points per thread
constexpr int MBLK = NT * TP;      // 2048
constexpr int MC   = M / MBLK;     // 2
constexpr int NBLK = 128;          // completed points per block
constexpr int NC   = N / NBLK;     // 64 n-chunks
constexpr int ROWS = B * M;        // 32768 (b,m) rows
constexpr float FMAX = 3.402823466e38f;

__global__ __launch_bounds__(NT, 4) void pml_main(const float* __restrict__ completed,
                                                  const float* __restrict__ partial,
                                                  float* __restrict__ ws,
                                                  float* __restrict__ out) {
    __shared__ float4 cs[NBLK];
    const int t     = threadIdx.x;
    const int b     = blockIdx.z;
    const int mBase = blockIdx.y * MBLK;
    const int nBase = blockIdx.x * NBLK;

    if (blockIdx.x == 0 && blockIdx.y == 0 && b == 0 && t == 0)
        out[0] = 0.0f;   // reduce kernel runs strictly after this one

    // Stage: first NBLK threads load one completed point each.
    if (t < NBLK) {
        const float* cp = completed + (size_t)(b * N + nBase + t) * 3;
        float x = cp[0], y = cp[1], z = cp[2];
        cs[t] = make_float4(x, y, z, 0.5f * (x * x + y * y + z * z));
    }
    __syncthreads();

    const int m0 = mBase + t * TP;
    // 8 points * 12 B = 96 B per thread, 16B-aligned -> 6 float4 loads.
    const float4* pv = (const float4*)(partial + (size_t)(b * M + m0) * 3);
    float4 v0 = pv[0], v1 = pv[1], v2 = pv[2], v3 = pv[3], v4 = pv[4], v5 = pv[5];

    float nx[TP], ny[TP], nz[TP], fm[TP];
    nx[0] = -v0.x; ny[0] = -v0.y; nz[0] = -v0.z;
    nx[1] = -v0.w; ny[1] = -v1.x; nz[1] = -v1.y;
    nx[2] = -v1.z; ny[2] = -v1.w; nz[2] = -v2.x;
    nx[3] = -v2.y; ny[3] = -v2.z; nz[3] = -v2.w;
    nx[4] = -v3.x; ny[4] = -v3.y; nz[4] = -v3.z;
    nx[5] = -v3.w; ny[5] = -v4.x; nz[5] = -v4.y;
    nx[6] = -v4.z; ny[6] = -v4.w; nz[6] = -v5.x;
    nx[7] = -v5.y; ny[7] = -v5.z; nz[7] = -v5.w;
#pragma unroll
    for (int p = 0; p < TP; ++p) fm[p] = FMAX;

#pragma unroll 4
    for (int j = 0; j < NBLK; j += 2) {
        float4 c0 = cs[j];       // wave-uniform -> LDS broadcast, conflict-free
        float4 c1 = cs[j + 1];
#pragma unroll
        for (int p = 0; p < TP; ++p) {
            float f0 = fmaf(nx[p], c0.x, fmaf(ny[p], c0.y, fmaf(nz[p], c0.z, c0.w)));
            float f1 = fmaf(nx[p], c1.x, fmaf(ny[p], c1.y, fmaf(nz[p], c1.z, c1.w)));
            fm[p] = fminf(fm[p], fminf(f0, f1));   // v_min3_f32
        }
    }

    // store per-chunk f_min (d2 / sqrt deferred to reduce pass)
    float4* wsv = (float4*)(ws + (size_t)blockIdx.x * ROWS + b * M + m0);
    wsv[0] = make_float4(fm[0], fm[1], fm[2], fm[3]);
    wsv[1] = make_float4(fm[4], fm[5], fm[6], fm[7]);
}

// Reduce: thread q owns rows 4q..4q+3; ws is c-major [NC][ROWS], so the 4 rows
// are one float4 per chunk-slice -> fully coalesced float4 loads, lane-parallel min.
constexpr int RT      = 64;             // 1 wave per block
constexpr int RQUADS  = ROWS / 4;       // 8192 row-quads
constexpr int RBLOCKS = RQUADS / RT;    // 128 blocks -> 128 CUs touched

__global__ __launch_bounds__(RT) void pml_reduce(const float* __restrict__ ws,
                                                 const float* __restrict__ partial,
                                                 float* __restrict__ out) {
    const int q = blockIdx.x * RT + threadIdx.x;   // row-quad index
    const float4* wsv = (const float4*)ws;

    float4 m = make_float4(FMAX, FMAX, FMAX, FMAX);
#pragma unroll 16
    for (int c = 0; c < NC; ++c) {
        float4 v = wsv[(size_t)c * RQUADS + q];
        m.x = fminf(m.x, v.x);
        m.y = fminf(m.y, v.y);
        m.z = fminf(m.z, v.z);
        m.w = fminf(m.w, v.w);
    }

    // 4 partial points = 48 B = 3 aligned float4 loads.
    const float4* pp = (const float4*)partial + (size_t)q * 3;
    float4 a = pp[0], bb = pp[1], cc = pp[2];

    float psq0 = a.x * a.x + a.y * a.y + a.z * a.z;
    float psq1 = a.w * a.w + bb.x * bb.x + bb.y * bb.y;
    float psq2 = bb.z * bb.z + bb.w * bb.w + cc.x * cc.x;
    float psq3 = cc.y * cc.y + cc.z * cc.z + cc.w * cc.w;

    float s = sqrtf(fmaxf(fmaf(2.0f, m.x, psq0), 0.0f))
            + sqrtf(fmaxf(fmaf(2.0f, m.y, psq1), 0.0f))
            + sqrtf(fmaxf(fmaf(2.0f, m.z, psq2), 0.0f))
            + sqrtf(fmaxf(fmaf(2.0f, m.w, psq3), 0.0f));

#pragma unroll
    for (int off = 32; off > 0; off >>= 1) s += __shfl_down(s, off);

    if (threadIdx.x == 0)
        atomicAdd(out, s * (1.0f / (float)ROWS));
}

extern "C" void kernel_launch(void* const* d_in, const int* in_sizes, int n_in,
                              void* d_out, int out_size, void* d_ws, size_t ws_size,
                              hipStream_t stream) {
    const float* completed = (const float*)d_in[0];  // (8, 8192, 3)
    const float* partial   = (const float*)d_in[1];  // (8, 4096, 3)
    float* out = (float*)d_out;
    float* ws  = (float*)d_ws;   // uses NC * ROWS * 4 = 8 MB

    dim3 grid(NC, MC, B);        // (64, 2, 8) = 1024 blocks, 4 blocks/CU
    pml_main<<<grid, NT, 0, stream>>>(completed, partial, ws, out);
    pml_reduce<<<RBLOCKS, RT, 0, stream>>>(ws, partial, out);
}